// Round 1
// 161.529 us; speedup vs baseline: 1.0690x; 1.0690x over previous
//
#include <hip/hip_runtime.h>

// Causal linear attention (chunked scan), bf16 MFMA end-to-end.
// q = softmax(x Wq^T), k = softmax(x Wk^T), v = x Wv^T   (one fused MFMA GEMM)
// T_c = sum_{t in chunk} v_t^T (x) k_t  (= S_c^T)        (MFMA, pass A)
// Tpre = exclusive prefix of T_c over chunks (fp32 scan -> bf16)  (pass B)
// out = Q @ Tpre^T + tril(Q K^T) @ V                     (MFMA, pass C)

constexpr int DIM  = 1024;
constexpr int H    = 16;
constexpr int DH   = 64;
constexpr int LSEQ = 2048;
constexpr int NB   = 2;
constexpr int MTOK = NB * LSEQ;   // 4096 tokens
constexpr int CS   = 64;          // chunk size
constexpr int NC   = LSEQ / CS;   // 32 chunks

typedef __bf16 bf16x8 __attribute__((ext_vector_type(8)));
typedef float floatx4 __attribute__((ext_vector_type(4)));
typedef unsigned short ushort_t;

__device__ __forceinline__ ushort_t f2bf(float f) {
  unsigned int u = __float_as_uint(f);
  u += 0x7FFFu + ((u >> 16) & 1u);   // RTNE
  return (ushort_t)(u >> 16);
}
__device__ __forceinline__ float bf2f(ushort_t b) {
  return __uint_as_float(((unsigned int)b) << 16);
}

__device__ __forceinline__ void async16(void* lds, const void* g) {
  __builtin_amdgcn_global_load_lds(
      (const __attribute__((address_space(1))) unsigned int*)g,
      (__attribute__((address_space(3))) unsigned int*)lds, 16, 0, 0);
}

// read a bf16x8 fragment from a transposed stride-33-uint LDS array
__device__ __forceinline__ bf16x8 tfrag(const unsigned int* T, int row, int uoff) {
  union { bf16x8 v; unsigned int u[4]; } r;
  const unsigned int* p = T + row * 33 + uoff;
  r.u[0] = p[0]; r.u[1] = p[1]; r.u[2] = p[2]; r.u[3] = p[3];
  return r.v;
}

// transpose a 64x64 bf16 tile (global, row stride DIM) into stride-33-uint LDS
__device__ __forceinline__ void transpose_tile(const ushort_t* g, unsigned int* TT, int tid) {
  const int ic = tid & 7, tp = tid >> 3;       // tp 0..31, ic 0..7
  const ushort_t* r0 = g + (size_t)(2 * tp) * DIM + ic * 8;
  union { uint4 q; ushort_t u[8]; } a0, a1;
  a0.q = *(const uint4*)r0;
  a1.q = *(const uint4*)(r0 + DIM);
#pragma unroll
  for (int j = 0; j < 8; j++)
    TT[(8 * ic + j) * 33 + tp] = (unsigned int)a0.u[j] | ((unsigned int)a1.u[j] << 16);
}

// ------------- cast fp32 -> bf16 for query/key and the three weights --------
__global__ __launch_bounds__(256) void cast_all(const float* __restrict__ q,
                                                const float* __restrict__ k,
                                                const float* __restrict__ wq,
                                                const float* __restrict__ wk,
                                                const float* __restrict__ wv,
                                                ushort_t* __restrict__ xbf,
                                                ushort_t* __restrict__ wbf) {
  const int seg = blockIdx.y;
  const float* src;
  ushort_t* dst;
  int n4;
  if (seg == 0)      { src = q;  dst = xbf;                  n4 = (4 << 20) / 4; }
  else if (seg == 1) { src = k;  dst = xbf + (4 << 20);      n4 = (4 << 20) / 4; }
  else if (seg == 2) { src = wq; dst = wbf;                  n4 = (1 << 20) / 4; }
  else if (seg == 3) { src = wk; dst = wbf + (1 << 20);      n4 = (1 << 20) / 4; }
  else               { src = wv; dst = wbf + (2 << 20);      n4 = (1 << 20) / 4; }
  for (int i = blockIdx.x * 256 + threadIdx.x; i < n4; i += gridDim.x * 256) {
    const float4 f = ((const float4*)src)[i];
    ((ushort4*)dst)[i] = make_ushort4(f2bf(f.x), f2bf(f.y), f2bf(f.z), f2bf(f.w));
  }
}

// ----- fused bf16 MFMA GEMM NT: z in {0:q,1:k,2:v}, tile 128x128, BK=32 -----
// 4 waves in 2x2; each wave 64x64 (4x4 MFMA / K-iter). In-register per-head
// softmax epilogue for z<2 (wave's 64 cols == one head).
// Double-buffered stage (T3 minimum 2-phase): prefetch tile k+1 issued BEFORE
// the ds_read+MFMA of tile k; one barrier per K-step (its vmcnt(0) drain
// completes the prefetch).
struct Stage { ushort_t As[128 * 32]; ushort_t Ws[128 * 32]; };
union SMemU { Stage st[2]; ushort_t CsB[128 * 136]; };

__global__ __launch_bounds__(256) void gemm_fused(const ushort_t* __restrict__ xbf,
                                                  const ushort_t* __restrict__ wbf,
                                                  ushort_t* __restrict__ qp,
                                                  ushort_t* __restrict__ kp,
                                                  ushort_t* __restrict__ vp) {
  __shared__ SMemU sm;
  const int tid  = threadIdx.x;
  const int z    = blockIdx.z;
  const ushort_t* A = xbf + (z ? (size_t)(4 << 20) : 0);
  const ushort_t* W = wbf + (size_t)z * (1 << 20);
  ushort_t* C = (z == 0) ? qp : ((z == 1) ? kp : vp);
  const int bn   = blockIdx.x * 128;
  const int bm   = blockIdx.y * 128;
  const int lane = tid & 63;
  const int wid  = tid >> 6;
  const int wm   = wid >> 1, wn = wid & 1;
  const int row16 = lane & 15, quad = lane >> 4;

  floatx4 acc[4][4] = {};

  const ushort_t* gA0 = A + (size_t)(bm + (tid >> 2)) * DIM + (tid & 3) * 8;
  const ushort_t* gA1 = A + (size_t)(bm + 64 + (tid >> 2)) * DIM + (tid & 3) * 8;
  const ushort_t* gW0 = W + (size_t)(bn + (tid >> 2)) * DIM + (tid & 3) * 8;
  const ushort_t* gW1 = W + (size_t)(bn + 64 + (tid >> 2)) * DIM + (tid & 3) * 8;

  // prologue: stage tile 0 into buffer 0
  {
    Stage& s0 = sm.st[0];
    async16(s0.As + tid * 8,         gA0);
    async16(s0.As + (tid + 256) * 8, gA1);
    async16(s0.Ws + tid * 8,         gW0);
    async16(s0.Ws + (tid + 256) * 8, gW1);
  }
  __syncthreads();   // drains vmcnt(0): tile 0 staged

  int cur = 0;
  for (int k0 = 0; k0 < DIM; k0 += 32) {
    // issue prefetch of tile k0+32 into the other buffer (overlaps with MFMA)
    if (k0 + 32 < DIM) {
      Stage& sn = sm.st[cur ^ 1];
      async16(sn.As + tid * 8,         gA0 + k0 + 32);
      async16(sn.As + (tid + 256) * 8, gA1 + k0 + 32);
      async16(sn.Ws + tid * 8,         gW0 + k0 + 32);
      async16(sn.Ws + (tid + 256) * 8, gW1 + k0 + 32);
    }
    const Stage& s = sm.st[cur];
    bf16x8 a[4], b[4];
#pragma unroll
    for (int mt = 0; mt < 4; mt++)
      a[mt] = *(const bf16x8*)&s.As[(wm * 64 + mt * 16 + row16) * 32 + quad * 8];
#pragma unroll
    for (int nt = 0; nt < 4; nt++)
      b[nt] = *(const bf16x8*)&s.Ws[(wn * 64 + nt * 16 + row16) * 32 + quad * 8];
#pragma unroll
    for (int mt = 0; mt < 4; mt++)
#pragma unroll
      for (int nt = 0; nt < 4; nt++)
        acc[mt][nt] = __builtin_amdgcn_mfma_f32_16x16x32_bf16(a[mt], b[nt], acc[mt][nt], 0, 0, 0);
    __syncthreads();   // one barrier/K-step: drains prefetch, fences LDS reuse
    cur ^= 1;
  }
  // final barrier of the loop already fenced all LDS reads -> CsB reuse is safe

  if (z < 2) {
    // in-register per-head softmax: row (mt,quad,r) spans nt regs x 16 lanes
#pragma unroll
    for (int mt = 0; mt < 4; mt++)
#pragma unroll
      for (int r = 0; r < 4; r++) {
        float m = fmaxf(fmaxf(acc[mt][0][r], acc[mt][1][r]),
                        fmaxf(acc[mt][2][r], acc[mt][3][r]));
#pragma unroll
        for (int o = 1; o < 16; o <<= 1) m = fmaxf(m, __shfl_xor(m, o, 64));
        float e[4], s = 0.f;
#pragma unroll
        for (int nt = 0; nt < 4; nt++) { e[nt] = __expf(acc[mt][nt][r] - m); s += e[nt]; }
#pragma unroll
        for (int o = 1; o < 16; o <<= 1) s += __shfl_xor(s, o, 64);
        const float inv = 1.f / s;
#pragma unroll
        for (int nt = 0; nt < 4; nt++) acc[mt][nt][r] = e[nt] * inv;
      }
  }

  // repack to bf16 in LDS (stride 136), then coalesced 16B stores
#pragma unroll
  for (int mt = 0; mt < 4; mt++)
#pragma unroll
    for (int nt = 0; nt < 4; nt++)
#pragma unroll
      for (int r = 0; r < 4; r++)
        sm.CsB[(wm * 64 + mt * 16 + quad * 4 + r) * 136 + wn * 64 + nt * 16 + row16] =
            f2bf(acc[mt][nt][r]);
  __syncthreads();
#pragma unroll
  for (int it = 0; it < 8; it++) {
    const int ch = tid + it * 256;        // 0..2047 = 128 rows x 16 chunks
    const int row = ch >> 4, ic = ch & 15;
    const uint4 val = *(const uint4*)&sm.CsB[row * 136 + ic * 8];
    *(uint4*)&C[(size_t)(bm + row) * DIM + bn + ic * 8] = val;
  }
}

// ------- pass A: T_c[j][i] = sum_t V[t][j] K[t][i]  (MFMA, fp32 out) --------
__global__ __launch_bounds__(256) void chunk_T(const ushort_t* __restrict__ kp,
                                               const ushort_t* __restrict__ vp,
                                               float* __restrict__ cs) {
  __shared__ unsigned int KT[64 * 33];
  __shared__ unsigned int VT[64 * 33];
  const int c = blockIdx.x, h = blockIdx.y, n = blockIdx.z;
  const int tid = threadIdx.x;
  const size_t gbase = ((size_t)(n * LSEQ + c * CS)) * DIM + h * DH;

  transpose_tile(kp + gbase, KT, tid);
  transpose_tile(vp + gbase, VT, tid);
  __syncthreads();

  const int lane = tid & 63, wid = tid >> 6;
  const int row16 = lane & 15, quad = lane >> 4;

  floatx4 acc[4] = {};
#pragma unroll
  for (int ks = 0; ks < 2; ks++) {
    const bf16x8 a = tfrag(VT, wid * 16 + row16, ks * 16 + quad * 4);
#pragma unroll
    for (int nt = 0; nt < 4; nt++) {
      const bf16x8 b = tfrag(KT, nt * 16 + row16, ks * 16 + quad * 4);
      acc[nt] = __builtin_amdgcn_mfma_f32_16x16x32_bf16(a, b, acc[nt], 0, 0, 0);
    }
  }
  float* outp = cs + ((size_t)((n * H + h) * NC + c)) * (DH * DH);
#pragma unroll
  for (int nt = 0; nt < 4; nt++)
#pragma unroll
    for (int r = 0; r < 4; r++)
      outp[(wid * 16 + quad * 4 + r) * DH + nt * 16 + row16] = acc[nt][r];
}

// ------- pass B: exclusive prefix over chunks (fp32 scan -> bf16 out) -------
__global__ __launch_bounds__(256) void prefix_chunks(const float* __restrict__ cs,
                                                     ushort_t* __restrict__ csb) {
  const int nh = blockIdx.x >> 4;
  const int e  = (blockIdx.x & 15) * 256 + threadIdx.x;   // 0..4095
  const float* bf_ = cs + (size_t)nh * NC * (DH * DH) + e;
  ushort_t* bb = csb + (size_t)nh * NC * (DH * DH) + e;
  float run = 0.f;
#pragma unroll
  for (int c = 0; c < NC; c++) {
    const float cur = bf_[(size_t)c * (DH * DH)];
    bb[(size_t)c * (DH * DH)] = f2bf(run);
    run += cur;
  }
}

// ---- pass C: out = Q @ Tpre^T + tril(Q K^T) @ V  (MFMA, fp32 out) ----------
__global__ __launch_bounds__(256) void attn_mfma(const ushort_t* __restrict__ qp,
                                                 const ushort_t* __restrict__ kp,
                                                 const ushort_t* __restrict__ vp,
                                                 const ushort_t* __restrict__ csb,
                                                 float* __restrict__ out) {
  __shared__ ushort_t Qs[64 * 72];
  __shared__ ushort_t Ks[64 * 72];
  __shared__ ushort_t Ts[64 * 72];
  __shared__ unsigned int VT[64 * 33];
  __shared__ ushort_t Pb[64 * 72];
  const int c = blockIdx.x, h = blockIdx.y, n = blockIdx.z;
  const int tid = threadIdx.x;
  const size_t gbase = ((size_t)(n * LSEQ + c * CS)) * DIM + h * DH;
  const size_t cbase = ((size_t)((n * H + h) * NC + c)) * (DH * DH);

#pragma unroll
  for (int it = 0; it < 2; it++) {
    const int ch = tid + it * 256;        // 0..511
    const int row = ch >> 3, ic = ch & 7;
    *(uint4*)&Qs[row * 72 + ic * 8] = *(const uint4*)&qp[gbase + (size_t)row * DIM + ic * 8];
    *(uint4*)&Ks[row * 72 + ic * 8] = *(const uint4*)&kp[gbase + (size_t)row * DIM + ic * 8];
    *(uint4*)&Ts[row * 72 + ic * 8] = *(const uint4*)&csb[cbase + (size_t)row * DH + ic * 8];
  }
  transpose_tile(vp + gbase, VT, tid);
  __syncthreads();

  const int lane = tid & 63, wid = tid >> 6;
  const int row16 = lane & 15, quad = lane >> 4;
  const int t0 = wid * 16;

  floatx4 acc[4] = {};
  floatx4 pacc[4] = {};

#pragma unroll
  for (int ks = 0; ks < 2; ks++) {
    const bf16x8 aq = *(const bf16x8*)&Qs[(t0 + row16) * 72 + ks * 32 + quad * 8];
#pragma unroll
    for (int nt = 0; nt < 4; nt++) {
      const bf16x8 bt = *(const bf16x8*)&Ts[(nt * 16 + row16) * 72 + ks * 32 + quad * 8];
      acc[nt] = __builtin_amdgcn_mfma_f32_16x16x32_bf16(aq, bt, acc[nt], 0, 0, 0);
      const bf16x8 bk = *(const bf16x8*)&Ks[(nt * 16 + row16) * 72 + ks * 32 + quad * 8];
      pacc[nt] = __builtin_amdgcn_mfma_f32_16x16x32_bf16(aq, bk, pacc[nt], 0, 0, 0);
    }
  }
#pragma unroll
  for (int nt = 0; nt < 4; nt++)
#pragma unroll
    for (int r = 0; r < 4; r++) {
      const int t = t0 + quad * 4 + r, s = nt * 16 + row16;
      Pb[t * 72 + s] = f2bf((s <= t) ? pacc[nt][r] : 0.f);
    }
  __syncthreads();

#pragma unroll
  for (int ks = 0; ks < 2; ks++) {
    const bf16x8 ap = *(const bf16x8*)&Pb[(t0 + row16) * 72 + ks * 32 + quad * 8];
#pragma unroll
    for (int nt = 0; nt < 4; nt++) {
      const bf16x8 bv = tfrag(VT, nt * 16 + row16, ks * 16 + quad * 4);
      acc[nt] = __builtin_amdgcn_mfma_f32_16x16x32_bf16(ap, bv, acc[nt], 0, 0, 0);
    }
  }

#pragma unroll
  for (int nt = 0; nt < 4; nt++)
#pragma unroll
    for (int r = 0; r < 4; r++)
      out[gbase + (size_t)(t0 + quad * 4 + r) * DIM + nt * 16 + row16] = acc[nt][r];
}

extern "C" void kernel_launch(void* const* d_in, const int* in_sizes, int n_in,
                              void* d_out, int out_size, void* d_ws, size_t ws_size,
                              hipStream_t stream) {
  const float* query = (const float*)d_in[0];
  const float* key   = (const float*)d_in[1];
  const float* Wq    = (const float*)d_in[2];
  const float* Wk    = (const float*)d_in[3];
  const float* Wv    = (const float*)d_in[4];
  float* out = (float*)d_out;

  // d_ws: [qp 8MB bf16][kp 8MB][vp 8MB][cs 16MB f32][csb 8MB bf16] = 48MB
  // xbf (16MB) overlays cs; wbf (6MB) overlays d_out (dead until attn_mfma)
  const size_t PM = (size_t)4 << 20;                 // 4M elements
  ushort_t* qp = (ushort_t*)d_ws;
  ushort_t* kp = qp + PM;
  ushort_t* vp = kp + PM;
  float*    cs = (float*)(vp + PM);
  ushort_t* csb = (ushort_t*)(cs + PM);
  ushort_t* xbf = (ushort_t*)cs;
  ushort_t* wbf = (ushort_t*)out;

  cast_all<<<dim3(512, 5), 256, 0, stream>>>(query, key, Wq, Wk, Wv, xbf, wbf);

  gemm_fused<<<dim3(DIM / 128, MTOK / 128, 3), 256, 0, stream>>>(xbf, wbf, qp, kp, vp);

  chunk_T<<<dim3(NC, H, NB), 256, 0, stream>>>(kp, vp, cs);
  prefix_chunks<<<dim3(NB * H * 16), 256, 0, stream>>>(cs, csb);
  attn_mfma<<<dim3(NC, H, NB), 256, 0, stream>>>(qp, kp, vp, csb, out);
}

// Round 2
// 158.243 us; speedup vs baseline: 1.0912x; 1.0208x over previous
//
#include <hip/hip_runtime.h>

// Causal linear attention (chunked scan), bf16 MFMA end-to-end.
// q = softmax(x Wq^T), k = softmax(x Wk^T), v = x Wv^T   (one fused MFMA GEMM)
// T_c = sum_{t in chunk} v_t^T (x) k_t  (= S_c^T)        (MFMA, pass A)
// Tpre = exclusive prefix of T_c over chunks (fp32 scan -> bf16)  (pass B)
// out = Q @ Tpre^T + tril(Q K^T) @ V                     (MFMA, pass C)

constexpr int DIM  = 1024;
constexpr int H    = 16;
constexpr int DH   = 64;
constexpr int LSEQ = 2048;
constexpr int NB   = 2;
constexpr int MTOK = NB * LSEQ;   // 4096 tokens
constexpr int CS   = 64;          // chunk size
constexpr int NC   = LSEQ / CS;   // 32 chunks

typedef __bf16 bf16x8 __attribute__((ext_vector_type(8)));
typedef float floatx4 __attribute__((ext_vector_type(4)));
typedef unsigned short ushort_t;

__device__ __forceinline__ ushort_t f2bf(float f) {
  unsigned int u = __float_as_uint(f);
  u += 0x7FFFu + ((u >> 16) & 1u);   // RTNE
  return (ushort_t)(u >> 16);
}
__device__ __forceinline__ float bf2f(ushort_t b) {
  return __uint_as_float(((unsigned int)b) << 16);
}

__device__ __forceinline__ void async16(void* lds, const void* g) {
  __builtin_amdgcn_global_load_lds(
      (const __attribute__((address_space(1))) unsigned int*)g,
      (__attribute__((address_space(3))) unsigned int*)lds, 16, 0, 0);
}

// read a bf16x8 fragment from a transposed stride-33-uint LDS array
__device__ __forceinline__ bf16x8 tfrag(const unsigned int* T, int row, int uoff) {
  union { bf16x8 v; unsigned int u[4]; } r;
  const unsigned int* p = T + row * 33 + uoff;
  r.u[0] = p[0]; r.u[1] = p[1]; r.u[2] = p[2]; r.u[3] = p[3];
  return r.v;
}

// transpose a 64x64 bf16 tile (global, row stride DIM) into stride-33-uint LDS
__device__ __forceinline__ void transpose_tile(const ushort_t* g, unsigned int* TT, int tid) {
  const int ic = tid & 7, tp = tid >> 3;       // tp 0..31, ic 0..7
  const ushort_t* r0 = g + (size_t)(2 * tp) * DIM + ic * 8;
  union { uint4 q; ushort_t u[8]; } a0, a1;
  a0.q = *(const uint4*)r0;
  a1.q = *(const uint4*)(r0 + DIM);
#pragma unroll
  for (int j = 0; j < 8; j++)
    TT[(8 * ic + j) * 33 + tp] = (unsigned int)a0.u[j] | ((unsigned int)a1.u[j] << 16);
}

// ------------- cast fp32 -> bf16 for query/key and the three weights --------
__global__ __launch_bounds__(256) void cast_all(const float* __restrict__ q,
                                                const float* __restrict__ k,
                                                const float* __restrict__ wq,
                                                const float* __restrict__ wk,
                                                const float* __restrict__ wv,
                                                ushort_t* __restrict__ xbf,
                                                ushort_t* __restrict__ wbf) {
  const int seg = blockIdx.y;
  const float* src;
  ushort_t* dst;
  int n4;
  if (seg == 0)      { src = q;  dst = xbf;                  n4 = (4 << 20) / 4; }
  else if (seg == 1) { src = k;  dst = xbf + (4 << 20);      n4 = (4 << 20) / 4; }
  else if (seg == 2) { src = wq; dst = wbf;                  n4 = (1 << 20) / 4; }
  else if (seg == 3) { src = wk; dst = wbf + (1 << 20);      n4 = (1 << 20) / 4; }
  else               { src = wv; dst = wbf + (2 << 20);      n4 = (1 << 20) / 4; }
  for (int i = blockIdx.x * 256 + threadIdx.x; i < n4; i += gridDim.x * 256) {
    const float4 f = ((const float4*)src)[i];
    ((ushort4*)dst)[i] = make_ushort4(f2bf(f.x), f2bf(f.y), f2bf(f.z), f2bf(f.w));
  }
}

// ----- fused bf16 MFMA GEMM NT: z in {0:q,1:k,2:v}, tile 128x128, BK=32 -----
// 4 waves in 2x2; each wave 64x64 (4x4 MFMA / K-iter). In-register per-head
// softmax epilogue for z<2 (wave's 64 cols == one head).
// 3-stage LDS pipeline, counted vmcnt(4) + raw s_barrier (loads for tiles
// t+1/t+2 stay in flight across the barrier -- never drained in the loop).
// Bank-conflict fix (T2, rule #21): LDS stays linear (global_load_lds writes
// base+lane*16); the GLOBAL source 16B-chunk is XOR-permuted per row with
// x(r) = (r ^ (r>>2)) & 3, and fragment reads apply the same XOR. Each 8-lane
// LDS service phase then hits 8 distinct bank-quads (was 4-way conflict).
struct Stage { ushort_t As[128 * 32]; ushort_t Ws[128 * 32]; };
union SMemU { Stage st[3]; ushort_t CsB[128 * 136]; };

__global__ __launch_bounds__(256) void gemm_fused(const ushort_t* __restrict__ xbf,
                                                  const ushort_t* __restrict__ wbf,
                                                  ushort_t* __restrict__ qp,
                                                  ushort_t* __restrict__ kp,
                                                  ushort_t* __restrict__ vp) {
  __shared__ SMemU sm;
  const int tid  = threadIdx.x;
  const int z    = blockIdx.z;
  const ushort_t* A = xbf + (z ? (size_t)(4 << 20) : 0);
  const ushort_t* W = wbf + (size_t)z * (1 << 20);
  ushort_t* C = (z == 0) ? qp : ((z == 1) ? kp : vp);
  const int bn   = blockIdx.x * 128;
  const int bm   = blockIdx.y * 128;
  const int lane = tid & 63;
  const int wid  = tid >> 6;
  const int wm   = wid >> 1, wn = wid & 1;
  const int row16 = lane & 15, quad = lane >> 4;

  floatx4 acc[4][4] = {};

  // staging: thread tid owns physical LDS slot (row = tid>>2, chunk = tid&3);
  // it loads the global chunk (tid&3) ^ x(row) so that logical chunk c of row
  // r sits at physical chunk c ^ x(r).
  const int srow = tid >> 2;                               // 0..63
  const int cg   = (tid & 3) ^ ((srow ^ (srow >> 2)) & 3); // swizzled src chunk
  const ushort_t* gA0 = A + (size_t)(bm + srow) * DIM + cg * 8;
  const ushort_t* gA1 = A + (size_t)(bm + 64 + srow) * DIM + cg * 8;
  const ushort_t* gW0 = W + (size_t)(bn + srow) * DIM + cg * 8;
  const ushort_t* gW1 = W + (size_t)(bn + 64 + srow) * DIM + cg * 8;

#define STAGE(buf, koff)                                    \
  {                                                         \
    Stage& s_ = sm.st[buf];                                 \
    async16(s_.As + tid * 8,         gA0 + (koff));         \
    async16(s_.As + (tid + 256) * 8, gA1 + (koff));         \
    async16(s_.Ws + tid * 8,         gW0 + (koff));         \
    async16(s_.Ws + (tid + 256) * 8, gW1 + (koff));         \
  }

  // reader-side swizzled chunk (per-thread constant)
  const int qx   = quad ^ ((row16 ^ (row16 >> 2)) & 3);
  const int aoff = (wm * 64 + row16) * 32 + qx * 8;   // + mt*512
  const int boff = (wn * 64 + row16) * 32 + qx * 8;   // + nt*512

  // prologue: stage K-slabs 0 and 1 into buffers 0 and 1 (8 loads in flight)
  STAGE(0, 0);
  STAGE(1, 32);

  int cur = 0, pf = 2;
  for (int s = 0; s < 32; ++s) {
    // wait for own STAGE(s) to land (keep s+1 in flight), then sync
    if (s < 31) asm volatile("s_waitcnt vmcnt(4)" ::: "memory");
    else        asm volatile("s_waitcnt vmcnt(0)" ::: "memory");
    __builtin_amdgcn_s_barrier();
    // buf[pf] was consumed at step s-1 by all waves (their MFMAs issued
    // before they reached this barrier) -> safe to restage
    if (s + 2 < 32) STAGE(pf, (s + 2) * 32);

    const Stage& st = sm.st[cur];
    bf16x8 a[4], b[4];
#pragma unroll
    for (int mt = 0; mt < 4; mt++)
      a[mt] = *(const bf16x8*)&st.As[aoff + mt * 512];
#pragma unroll
    for (int nt = 0; nt < 4; nt++)
      b[nt] = *(const bf16x8*)&st.Ws[boff + nt * 512];
#pragma unroll
    for (int mt = 0; mt < 4; mt++)
#pragma unroll
      for (int nt = 0; nt < 4; nt++)
        acc[mt][nt] = __builtin_amdgcn_mfma_f32_16x16x32_bf16(a[mt], b[nt], acc[mt][nt], 0, 0, 0);

    cur = (cur == 2) ? 0 : cur + 1;
    pf  = (pf  == 2) ? 0 : pf + 1;
  }
#undef STAGE
  __syncthreads();   // all ds_reads done before LDS reuse as CsB

  if (z < 2) {
    // in-register per-head softmax: row (mt,quad,r) spans nt regs x 16 lanes
#pragma unroll
    for (int mt = 0; mt < 4; mt++)
#pragma unroll
      for (int r = 0; r < 4; r++) {
        float m = fmaxf(fmaxf(acc[mt][0][r], acc[mt][1][r]),
                        fmaxf(acc[mt][2][r], acc[mt][3][r]));
#pragma unroll
        for (int o = 1; o < 16; o <<= 1) m = fmaxf(m, __shfl_xor(m, o, 64));
        float e[4], s = 0.f;
#pragma unroll
        for (int nt = 0; nt < 4; nt++) { e[nt] = __expf(acc[mt][nt][r] - m); s += e[nt]; }
#pragma unroll
        for (int o = 1; o < 16; o <<= 1) s += __shfl_xor(s, o, 64);
        const float inv = 1.f / s;
#pragma unroll
        for (int nt = 0; nt < 4; nt++) acc[mt][nt][r] = e[nt] * inv;
      }
  }

  // repack to bf16 in LDS (stride 136), then coalesced 16B stores
#pragma unroll
  for (int mt = 0; mt < 4; mt++)
#pragma unroll
    for (int nt = 0; nt < 4; nt++)
#pragma unroll
      for (int r = 0; r < 4; r++)
        sm.CsB[(wm * 64 + mt * 16 + quad * 4 + r) * 136 + wn * 64 + nt * 16 + row16] =
            f2bf(acc[mt][nt][r]);
  __syncthreads();
#pragma unroll
  for (int it = 0; it < 8; it++) {
    const int ch = tid + it * 256;        // 0..2047 = 128 rows x 16 chunks
    const int row = ch >> 4, ic = ch & 15;
    const uint4 val = *(const uint4*)&sm.CsB[row * 136 + ic * 8];
    *(uint4*)&C[(size_t)(bm + row) * DIM + bn + ic * 8] = val;
  }
}

// ------- pass A: T_c[j][i] = sum_t V[t][j] K[t][i]  (MFMA, fp32 out) --------
__global__ __launch_bounds__(256) void chunk_T(const ushort_t* __restrict__ kp,
                                               const ushort_t* __restrict__ vp,
                                               float* __restrict__ cs) {
  __shared__ unsigned int KT[64 * 33];
  __shared__ unsigned int VT[64 * 33];
  const int c = blockIdx.x, h = blockIdx.y, n = blockIdx.z;
  const int tid = threadIdx.x;
  const size_t gbase = ((size_t)(n * LSEQ + c * CS)) * DIM + h * DH;

  transpose_tile(kp + gbase, KT, tid);
  transpose_tile(vp + gbase, VT, tid);
  __syncthreads();

  const int lane = tid & 63, wid = tid >> 6;
  const int row16 = lane & 15, quad = lane >> 4;

  floatx4 acc[4] = {};
#pragma unroll
  for (int ks = 0; ks < 2; ks++) {
    const bf16x8 a = tfrag(VT, wid * 16 + row16, ks * 16 + quad * 4);
#pragma unroll
    for (int nt = 0; nt < 4; nt++) {
      const bf16x8 b = tfrag(KT, nt * 16 + row16, ks * 16 + quad * 4);
      acc[nt] = __builtin_amdgcn_mfma_f32_16x16x32_bf16(a, b, acc[nt], 0, 0, 0);
    }
  }
  float* outp = cs + ((size_t)((n * H + h) * NC + c)) * (DH * DH);
#pragma unroll
  for (int nt = 0; nt < 4; nt++)
#pragma unroll
    for (int r = 0; r < 4; r++)
      outp[(wid * 16 + quad * 4 + r) * DH + nt * 16 + row16] = acc[nt][r];
}

// ------- pass B: exclusive prefix over chunks (fp32 scan -> bf16 out) -------
__global__ __launch_bounds__(256) void prefix_chunks(const float* __restrict__ cs,
                                                     ushort_t* __restrict__ csb) {
  const int nh = blockIdx.x >> 4;
  const int e  = (blockIdx.x & 15) * 256 + threadIdx.x;   // 0..4095
  const float* bf_ = cs + (size_t)nh * NC * (DH * DH) + e;
  ushort_t* bb = csb + (size_t)nh * NC * (DH * DH) + e;
  float run = 0.f;
#pragma unroll
  for (int c = 0; c < NC; c++) {
    const float cur = bf_[(size_t)c * (DH * DH)];
    bb[(size_t)c * (DH * DH)] = f2bf(run);
    run += cur;
  }
}

// ---- pass C: out = Q @ Tpre^T + tril(Q K^T) @ V  (MFMA, fp32 out) ----------
__global__ __launch_bounds__(256) void attn_mfma(const ushort_t* __restrict__ qp,
                                                 const ushort_t* __restrict__ kp,
                                                 const ushort_t* __restrict__ vp,
                                                 const ushort_t* __restrict__ csb,
                                                 float* __restrict__ out) {
  __shared__ ushort_t Qs[64 * 72];
  __shared__ ushort_t Ks[64 * 72];
  __shared__ ushort_t Ts[64 * 72];
  __shared__ unsigned int VT[64 * 33];
  __shared__ ushort_t Pb[64 * 72];
  const int c = blockIdx.x, h = blockIdx.y, n = blockIdx.z;
  const int tid = threadIdx.x;
  const size_t gbase = ((size_t)(n * LSEQ + c * CS)) * DIM + h * DH;
  const size_t cbase = ((size_t)((n * H + h) * NC + c)) * (DH * DH);

#pragma unroll
  for (int it = 0; it < 2; it++) {
    const int ch = tid + it * 256;        // 0..511
    const int row = ch >> 3, ic = ch & 7;
    *(uint4*)&Qs[row * 72 + ic * 8] = *(const uint4*)&qp[gbase + (size_t)row * DIM + ic * 8];
    *(uint4*)&Ks[row * 72 + ic * 8] = *(const uint4*)&kp[gbase + (size_t)row * DIM + ic * 8];
    *(uint4*)&Ts[row * 72 + ic * 8] = *(const uint4*)&csb[cbase + (size_t)row * DH + ic * 8];
  }
  transpose_tile(vp + gbase, VT, tid);
  __syncthreads();

  const int lane = tid & 63, wid = tid >> 6;
  const int row16 = lane & 15, quad = lane >> 4;
  const int t0 = wid * 16;

  floatx4 acc[4] = {};
  floatx4 pacc[4] = {};

#pragma unroll
  for (int ks = 0; ks < 2; ks++) {
    const bf16x8 aq = *(const bf16x8*)&Qs[(t0 + row16) * 72 + ks * 32 + quad * 8];
#pragma unroll
    for (int nt = 0; nt < 4; nt++) {
      const bf16x8 bt = *(const bf16x8*)&Ts[(nt * 16 + row16) * 72 + ks * 32 + quad * 8];
      acc[nt] = __builtin_amdgcn_mfma_f32_16x16x32_bf16(aq, bt, acc[nt], 0, 0, 0);
      const bf16x8 bk = *(const bf16x8*)&Ks[(nt * 16 + row16) * 72 + ks * 32 + quad * 8];
      pacc[nt] = __builtin_amdgcn_mfma_f32_16x16x32_bf16(aq, bk, pacc[nt], 0, 0, 0);
    }
  }
#pragma unroll
  for (int nt = 0; nt < 4; nt++)
#pragma unroll
    for (int r = 0; r < 4; r++) {
      const int t = t0 + quad * 4 + r, s = nt * 16 + row16;
      Pb[t * 72 + s] = f2bf((s <= t) ? pacc[nt][r] : 0.f);
    }
  __syncthreads();

#pragma unroll
  for (int ks = 0; ks < 2; ks++) {
    const bf16x8 ap = *(const bf16x8*)&Pb[(t0 + row16) * 72 + ks * 32 + quad * 8];
#pragma unroll
    for (int nt = 0; nt < 4; nt++) {
      const bf16x8 bv = tfrag(VT, nt * 16 + row16, ks * 16 + quad * 4);
      acc[nt] = __builtin_amdgcn_mfma_f32_16x16x32_bf16(ap, bv, acc[nt], 0, 0, 0);
    }
  }

#pragma unroll
  for (int nt = 0; nt < 4; nt++)
#pragma unroll
    for (int r = 0; r < 4; r++)
      out[gbase + (size_t)(t0 + quad * 4 + r) * DIM + nt * 16 + row16] = acc[nt][r];
}

extern "C" void kernel_launch(void* const* d_in, const int* in_sizes, int n_in,
                              void* d_out, int out_size, void* d_ws, size_t ws_size,
                              hipStream_t stream) {
  const float* query = (const float*)d_in[0];
  const float* key   = (const float*)d_in[1];
  const float* Wq    = (const float*)d_in[2];
  const float* Wk    = (const float*)d_in[3];
  const float* Wv    = (const float*)d_in[4];
  float* out = (float*)d_out;

  // d_ws: [qp 8MB bf16][kp 8MB][vp 8MB][cs 16MB f32][csb 8MB bf16] = 48MB
  // xbf (16MB) overlays cs; wbf (6MB) overlays d_out (dead until attn_mfma)
  const size_t PM = (size_t)4 << 20;                 // 4M elements
  ushort_t* qp = (ushort_t*)d_ws;
  ushort_t* kp = qp + PM;
  ushort_t* vp = kp + PM;
  float*    cs = (float*)(vp + PM);
  ushort_t* csb = (ushort_t*)(cs + PM);
  ushort_t* xbf = (ushort_t*)cs;
  ushort_t* wbf = (ushort_t*)out;

  cast_all<<<dim3(512, 5), 256, 0, stream>>>(query, key, Wq, Wk, Wv, xbf, wbf);

  gemm_fused<<<dim3(DIM / 128, MTOK / 128, 3), 256, 0, stream>>>(xbf, wbf, qp, kp, vp);

  chunk_T<<<dim3(NC, H, NB), 256, 0, stream>>>(kp, vp, cs);
  prefix_chunks<<<dim3(NB * H * 16), 256, 0, stream>>>(cs, csb);
  attn_mfma<<<dim3(NC, H, NB), 256, 0, stream>>>(qp, kp, vp, csb, out);
}